// Round 1
// baseline (263.962 us; speedup 1.0000x reference)
//
#include <hip/hip_runtime.h>
#include <hip/hip_bf16.h>

// Problem constants (match reference)
#define BB   128
#define CC   272
#define TT   512
#define DD1  320
#define DT   16    // d-rows per block

// out[b,d,t] = sum_c W[s_b, d, c] * X[b, c, t]
// Grid: (B, D1/DT) ; Block: 256 threads, each thread owns 2 consecutive t.
__global__ __launch_bounds__(256)
void subj_conv_f32(const float* __restrict__ X,
                   const int*   __restrict__ sidx,
                   const float* __restrict__ W,
                   float*       __restrict__ out) {
    const int b  = blockIdx.x;
    const int d0 = blockIdx.y * DT;
    const int s  = sidx[b];

    // W chunk transposed: Wt[c][i] = W[s, d0+i, c]. 272*16*4 = 17 KiB LDS.
    // Reads in the main loop are wave-uniform (broadcast) -> no bank conflicts.
    __shared__ float Wt[CC][DT];
    const float* Wbase = W + (size_t)(s * DD1 + d0) * CC;
    for (int idx = threadIdx.x; idx < CC * DT; idx += 256) {
        int i = idx / CC;        // d index
        int c = idx - i * CC;    // channel (consecutive threads -> consecutive c: coalesced gmem)
        Wt[c][i] = Wbase[(size_t)i * CC + c];
    }
    __syncthreads();

    const int t0 = threadIdx.x * 2;                 // 2 consecutive t per thread (float2, coalesced)
    const float* Xb = X + (size_t)b * CC * TT + t0;

    float acc[DT][2];
#pragma unroll
    for (int i = 0; i < DT; ++i) { acc[i][0] = 0.f; acc[i][1] = 0.f; }

#pragma unroll 4
    for (int c = 0; c < CC; ++c) {
        const float2 x = *(const float2*)(Xb + (size_t)c * TT);
#pragma unroll
        for (int i = 0; i < DT; i += 4) {
            const float4 w = *(const float4*)&Wt[c][i];   // broadcast ds_read_b128
            acc[i + 0][0] += w.x * x.x;  acc[i + 0][1] += w.x * x.y;
            acc[i + 1][0] += w.y * x.x;  acc[i + 1][1] += w.y * x.y;
            acc[i + 2][0] += w.z * x.x;  acc[i + 2][1] += w.z * x.y;
            acc[i + 3][0] += w.w * x.x;  acc[i + 3][1] += w.w * x.y;
        }
    }

    float* ob = out + ((size_t)b * DD1 + d0) * TT + t0;
#pragma unroll
    for (int i = 0; i < DT; ++i) {
        *(float2*)(ob + (size_t)i * TT) = make_float2(acc[i][0], acc[i][1]);
    }
}

extern "C" void kernel_launch(void* const* d_in, const int* in_sizes, int n_in,
                              void* d_out, int out_size, void* d_ws, size_t ws_size,
                              hipStream_t stream) {
    const float* X    = (const float*)d_in[0];   // [B, C, T] fp32
    const int*   sidx = (const int*)  d_in[1];   // [B] int32
    const float* W    = (const float*)d_in[2];   // [S, D1, C] fp32
    float*       out  = (float*)d_out;           // [B, D1, T] fp32

    dim3 grid(BB, DD1 / DT);   // 128 x 20
    dim3 block(256);
    subj_conv_f32<<<grid, block, 0, stream>>>(X, sidx, W, out);
}

// Round 3
// 198.221 us; speedup vs baseline: 1.3317x; 1.3317x over previous
//
#include <hip/hip_runtime.h>

// Problem constants
#define BB    128
#define CC    272
#define TT    512
#define DD1   320
#define KC    32      // K-chunk per LDS stage (one mfma K)
#define NCHUNK 9      // ceil(272/32) -> K padded to 288 with zeros (exact)
#define NT    64      // t-tile per block
#define LDA   40      // As row stride in elems (80B: 16B-aligned rows, odd bank stride)
#define LDB   40      // Bs row stride

typedef float  f32x4  __attribute__((ext_vector_type(4)));
typedef __bf16 bf16x4 __attribute__((ext_vector_type(4)));
typedef __bf16 bf16x8 __attribute__((ext_vector_type(8)));

// out[b,d,t] = sum_c W[s_b,d,c] * X[b,c,t]
// Block: 256 thr (4 waves). Grid: (B, T/NT). Each block: full D1 x NT tile.
// Per wave: 5 m-tiles x 4 n-tiles of 16x16, mfma_f32_16x16x32_bf16, K=288 (zero-pad).
__global__ __launch_bounds__(256)
void subj_conv_mfma(const float* __restrict__ X,
                    const int*   __restrict__ sidx,
                    const float* __restrict__ W,
                    float*       __restrict__ out) {
    const int b  = blockIdx.x;
    const int T0 = blockIdx.y * NT;
    const int s  = sidx[b];

    // A chunk: W[s, m, c0:c0+32] as bf16, [m][kk] (kk contiguous -> ds_read_b128 frags)
    __shared__ __bf16 As[DD1 * LDA];   // 320*40*2 = 25.6 KB
    // B chunk: X[b, c0:c0+32, T0:T0+64] TRANSPOSED to [n][kk] (B^T layout, same as m97 gemm_bt)
    __shared__ __bf16 Bs[NT * LDB];    // 64*40*2 = 5.1 KB

    const int tid  = threadIdx.x;
    const int lane = tid & 63;
    const int wv   = tid >> 6;         // 0..3 -> m-rows [wv*80, wv*80+80)
    const int quad = lane >> 4;        // 0..3
    const int l16  = lane & 15;

    f32x4 acc[5][4];
#pragma unroll
    for (int mt = 0; mt < 5; ++mt)
#pragma unroll
        for (int nt = 0; nt < 4; ++nt)
            acc[mt][nt] = (f32x4){0.f, 0.f, 0.f, 0.f};

    const float* Wb = W + (size_t)s * DD1 * CC;
    const float* Xb = X + (size_t)b * CC * TT + T0;

    for (int kc = 0; kc < NCHUNK; ++kc) {
        const int c0 = kc * KC;

        // ---- stage A: 320x32 fp32 -> bf16. 2560 float4-groups / 256 thr = 10 each.
        // m = g>>3, kk = (g&7)*4; W row is c-contiguous -> coalesced float4 reads,
        // kk-contiguous b64 LDS writes (no transpose needed).
#pragma unroll
        for (int p = 0; p < 10; ++p) {
            const int g  = tid + 256 * p;
            const int m  = g >> 3;
            const int kk = (g & 7) * 4;
            const int c  = c0 + kk;
            float4 v = make_float4(0.f, 0.f, 0.f, 0.f);
            if (c < CC) v = *(const float4*)(Wb + (size_t)m * CC + c);
            bf16x4 h = {(__bf16)v.x, (__bf16)v.y, (__bf16)v.z, (__bf16)v.w};
            *(bf16x4*)&As[m * LDA + kk] = h;
        }

        // ---- stage B: 32x64 fp32, transpose to Bs[t][c]. 512 groups / 256 thr = 2 each.
        // cr = g>>4 (channel row), t = (g&15)*4 -> coalesced float4 read along t,
        // 4 scalar b16 writes (transpose; conflicts tolerable, traffic is small).
#pragma unroll
        for (int p = 0; p < 2; ++p) {
            const int g  = tid + 256 * p;
            const int cr = g >> 4;
            const int t  = (g & 15) * 4;
            const int c  = c0 + cr;
            float4 v = make_float4(0.f, 0.f, 0.f, 0.f);
            if (c < CC) v = *(const float4*)(Xb + (size_t)c * TT + t);
            Bs[(t + 0) * LDB + cr] = (__bf16)v.x;
            Bs[(t + 1) * LDB + cr] = (__bf16)v.y;
            Bs[(t + 2) * LDB + cr] = (__bf16)v.z;
            Bs[(t + 3) * LDB + cr] = (__bf16)v.w;
        }

        __syncthreads();

        // ---- compute: b-frags once, then 5 m-tiles x 4 mfma
        bf16x8 bf[4];
#pragma unroll
        for (int nt = 0; nt < 4; ++nt)
            bf[nt] = *(const bf16x8*)&Bs[(nt * 16 + l16) * LDB + quad * 8];

#pragma unroll
        for (int mt = 0; mt < 5; ++mt) {
            const int m = (wv * 5 + mt) * 16 + l16;
            bf16x8 af = *(const bf16x8*)&As[m * LDA + quad * 8];
#pragma unroll
            for (int nt = 0; nt < 4; ++nt)
                acc[mt][nt] = __builtin_amdgcn_mfma_f32_16x16x32_bf16(
                    af, bf[nt], acc[mt][nt], 0, 0, 0);
        }

        __syncthreads();
    }

    // ---- epilogue: D[m = quad*4 + r][n = l16] per 16x16 tile
#pragma unroll
    for (int mt = 0; mt < 5; ++mt) {
        const int d = (wv * 5 + mt) * 16 + quad * 4;
#pragma unroll
        for (int nt = 0; nt < 4; ++nt) {
            float* ob = out + ((size_t)b * DD1 + d) * TT + T0 + nt * 16 + l16;
#pragma unroll
            for (int r = 0; r < 4; ++r)
                ob[(size_t)r * TT] = acc[mt][nt][r];
        }
    }
}

extern "C" void kernel_launch(void* const* d_in, const int* in_sizes, int n_in,
                              void* d_out, int out_size, void* d_ws, size_t ws_size,
                              hipStream_t stream) {
    const float* X    = (const float*)d_in[0];   // [B, C, T]
    const int*   sidx = (const int*)  d_in[1];   // [B]
    const float* W    = (const float*)d_in[2];   // [S, D1, C]
    float*       out  = (float*)d_out;           // [B, D1, T]

    dim3 grid(BB, TT / NT);   // 128 x 8
    dim3 block(256);
    subj_conv_mfma<<<grid, block, 0, stream>>>(X, sidx, W, out);
}

// Round 4
// 168.160 us; speedup vs baseline: 1.5697x; 1.1788x over previous
//
#include <hip/hip_runtime.h>

// Problem constants
#define BB    128
#define CC    272
#define TT    512
#define DD1   320
#define KC    32      // K-chunk per LDS stage (one mfma K)
#define NCHUNK 9      // ceil(272/32): K zero-padded to 288 (exact)
#define NT    64      // t-tile per block
#define MT    160     // d-tile per block (D1 split in 2)
#define LDA   40      // As row stride (80 B rows: 16B-aligned, odd dword stride)
#define LDB   40      // Bs row stride

typedef float  f32x4  __attribute__((ext_vector_type(4)));
typedef __bf16 bf16x4 __attribute__((ext_vector_type(4)));
typedef __bf16 bf16x8 __attribute__((ext_vector_type(8)));

// Raw barrier: orders LDS ops (lgkmcnt(0)) without draining vmcnt — keeps
// register-prefetch global loads in flight across the barrier.
#define BAR() asm volatile("s_waitcnt lgkmcnt(0)\ns_barrier" ::: "memory")

// out[b,d,t] = sum_c W[s_b,d,c] * X[b,c,t]
// Grid (B, T/NT, 2). Block 256 thr / 4 waves as 2(m) x 2(n).
// Per wave: 5 m-tiles x 2 n-tiles, mfma_f32_16x16x32_bf16, K-chunks pipelined
// with register prefetch (loads for chunk k+1 in flight during chunk k MFMAs).
__global__ __launch_bounds__(256, 4)
void subj_conv_mfma(const float* __restrict__ X,
                    const int*   __restrict__ sidx,
                    const float* __restrict__ W,
                    float*       __restrict__ out) {
    const int b  = blockIdx.x;
    const int T0 = blockIdx.y * NT;
    const int d0 = blockIdx.z * MT;
    const int s  = sidx[b];

    __shared__ __bf16 As[MT * LDA];   // 160*40*2 = 12.8 KB
    __shared__ __bf16 Bs[NT * LDB];   // 64*40*2  =  5.1 KB

    const int tid  = threadIdx.x;
    const int lane = tid & 63;
    const int wv   = tid >> 6;
    const int wm   = wv & 1;          // m-half of wave (80 rows)
    const int wn   = wv >> 1;         // n-half of wave (32 t)
    const int quad = lane >> 4;
    const int l16  = lane & 15;

    const float* Wb = W + ((size_t)s * DD1 + d0) * CC;
    const float* Xb = X + (size_t)b * CC * TT + T0;

    // A-stage mapping: g = tid + 256p (p<5): m = g>>3, kk = (g&7)*4
    const int am  = tid >> 3;         // +32 per p
    const int akk = (tid & 7) * 4;
    // B-stage mapping: g = tid + 256p (p<2): cr = g>>4, t4 = (g&15)*4
    const int bcr = tid >> 4;         // +16 per p
    const int bt  = (tid & 15) * 4;

    f32x4 acc[5][2];
#pragma unroll
    for (int mt = 0; mt < 5; ++mt) {
        acc[mt][0] = (f32x4){0.f, 0.f, 0.f, 0.f};
        acc[mt][1] = (f32x4){0.f, 0.f, 0.f, 0.f};
    }

    float4 pa[5];
    float4 pb[2];

    // ---- prefetch chunk 0
    {
        const int c0 = 0;
#pragma unroll
        for (int p = 0; p < 5; ++p) {
            const int m = am + 32 * p;
            pa[p] = *(const float4*)(Wb + (size_t)m * CC + (c0 + akk));
        }
#pragma unroll
        for (int p = 0; p < 2; ++p) {
            const int c = c0 + bcr + 16 * p;
            pb[p] = *(const float4*)(Xb + (size_t)c * TT + bt);
        }
    }

    for (int kc = 0; kc < NCHUNK; ++kc) {
        // ---- store phase: cvt prefetched regs -> LDS (vmcnt waits land here)
#pragma unroll
        for (int p = 0; p < 5; ++p) {
            const int m = am + 32 * p;
            bf16x4 h = {(__bf16)pa[p].x, (__bf16)pa[p].y,
                        (__bf16)pa[p].z, (__bf16)pa[p].w};
            *(bf16x4*)&As[m * LDA + akk] = h;
        }
#pragma unroll
        for (int p = 0; p < 2; ++p) {
            const int cr = bcr + 16 * p;
            Bs[(bt + 0) * LDB + cr] = (__bf16)pb[p].x;
            Bs[(bt + 1) * LDB + cr] = (__bf16)pb[p].y;
            Bs[(bt + 2) * LDB + cr] = (__bf16)pb[p].z;
            Bs[(bt + 3) * LDB + cr] = (__bf16)pb[p].w;
        }

        BAR();

        // ---- issue next chunk's loads NOW: in flight during MFMAs + barrier
        if (kc + 1 < NCHUNK) {
            const int c0 = (kc + 1) * KC;
#pragma unroll
            for (int p = 0; p < 5; ++p) {
                const int m = am + 32 * p;
                const int c = c0 + akk;
                float4 v = make_float4(0.f, 0.f, 0.f, 0.f);
                if (c < CC) v = *(const float4*)(Wb + (size_t)m * CC + c);
                pa[p] = v;
            }
#pragma unroll
            for (int p = 0; p < 2; ++p) {
                const int c = c0 + bcr + 16 * p;
                float4 v = make_float4(0.f, 0.f, 0.f, 0.f);
                if (c < CC) v = *(const float4*)(Xb + (size_t)c * TT + bt);
                pb[p] = v;
            }
        }

        // ---- compute phase
        bf16x8 bfr[2];
#pragma unroll
        for (int nt = 0; nt < 2; ++nt)
            bfr[nt] = *(const bf16x8*)&Bs[(wn * 32 + nt * 16 + l16) * LDB + quad * 8];

#pragma unroll
        for (int mt = 0; mt < 5; ++mt) {
            bf16x8 af = *(const bf16x8*)&As[(wm * 80 + mt * 16 + l16) * LDA + quad * 8];
#pragma unroll
            for (int nt = 0; nt < 2; ++nt)
                acc[mt][nt] = __builtin_amdgcn_mfma_f32_16x16x32_bf16(
                    af, bfr[nt], acc[mt][nt], 0, 0, 0);
        }

        BAR();
    }

    // ---- epilogue: D[m = quad*4 + r][n = l16]
#pragma unroll
    for (int mt = 0; mt < 5; ++mt) {
        const int d = d0 + wm * 80 + mt * 16 + quad * 4;
#pragma unroll
        for (int nt = 0; nt < 2; ++nt) {
            float* ob = out + ((size_t)b * DD1 + d) * TT + T0 + wn * 32 + nt * 16 + l16;
#pragma unroll
            for (int r = 0; r < 4; ++r)
                ob[(size_t)r * TT] = acc[mt][nt][r];
        }
    }
}

extern "C" void kernel_launch(void* const* d_in, const int* in_sizes, int n_in,
                              void* d_out, int out_size, void* d_ws, size_t ws_size,
                              hipStream_t stream) {
    const float* X    = (const float*)d_in[0];   // [B, C, T]
    const int*   sidx = (const int*)  d_in[1];   // [B]
    const float* W    = (const float*)d_in[2];   // [S, D1, C]
    float*       out  = (float*)d_out;           // [B, D1, T]

    dim3 grid(BB, TT / NT, 2);   // 128 x 8 x 2 = 2048 blocks
    dim3 block(256);
    subj_conv_mfma<<<grid, block, 0, stream>>>(X, sidx, W, out);
}

// Round 5
// 164.416 us; speedup vs baseline: 1.6055x; 1.0228x over previous
//
#include <hip/hip_runtime.h>

// Problem constants
#define BB    128
#define CC    272
#define TT    512
#define DD1   320
#define KC    32      // K-chunk per LDS stage (one mfma K)
#define NCHUNK 9      // ceil(272/32): K zero-padded to 288 (exact)
#define NT    64      // t-tile per block
#define MT    160     // d-tile per block (D1 split in 2)
#define LDA   40      // As row stride, bf16 elems (80 B: 16B-aligned, free-read banks)
#define LDB2  66      // Bs row stride, f32 elems (264 B: 8B-aligned, free-read banks)

typedef float  f32x4  __attribute__((ext_vector_type(4)));
typedef __bf16 bf16x4 __attribute__((ext_vector_type(4)));
typedef __bf16 bf16x8 __attribute__((ext_vector_type(8)));

// Raw barrier: orders LDS ops (lgkmcnt(0)) without draining vmcnt — keeps
// register-prefetch global loads in flight across the barrier.
#define BAR() asm volatile("s_waitcnt lgkmcnt(0)\ns_barrier" ::: "memory")

// out[b,d,t] = sum_c W[s_b,d,c] * X[b,c,t]
// Grid (B, T/NT, 2). Block 256 thr / 4 waves as 2(m) x 2(n).
// Double-buffered LDS; chunk k+1 held in regs during compute of k; chunk k+2
// loads issued after the reg->LDS store. One lgkm-only barrier per iter.
__global__ __launch_bounds__(256, 4)
void subj_conv_mfma(const float* __restrict__ X,
                    const int*   __restrict__ sidx,
                    const float* __restrict__ W,
                    float*       __restrict__ out) {
    const int b  = blockIdx.x;
    const int T0 = blockIdx.y * NT;
    const int d0 = blockIdx.z * MT;
    const int s  = sidx[b];

    __shared__ __bf16 As[2][MT * LDA];    // 2 x 12.8 KB, bf16 [m][kk]
    __shared__ float  Bs[2][KC * LDB2];   // 2 x 8.45 KB, fp32 NATURAL [c][t]

    const int tid  = threadIdx.x;
    const int lane = tid & 63;
    const int wv   = tid >> 6;
    const int wm   = wv & 1;          // m-half (80 rows)
    const int wn   = wv >> 1;         // n-half (32 t)
    const int quad = lane >> 4;
    const int l16  = lane & 15;

    const float* Wb = W + ((size_t)s * DD1 + d0) * CC;
    const float* Xb = X + (size_t)b * CC * TT + T0;

    // A staging map: p<5: m = (tid>>3)+32p, kk = (tid&7)*4
    const int am  = tid >> 3;
    const int akk = (tid & 7) * 4;
    // B staging map: p<2: c-row = (tid>>4)+16p, t = (tid&15)*4
    const int bcr = tid >> 4;
    const int bt  = (tid & 15) * 4;

    f32x4 acc[5][2];
#pragma unroll
    for (int mt = 0; mt < 5; ++mt) {
        acc[mt][0] = (f32x4){0.f, 0.f, 0.f, 0.f};
        acc[mt][1] = (f32x4){0.f, 0.f, 0.f, 0.f};
    }

    float4 pa[5];
    float4 pb[2];

    // ---- issue global loads for chunk at c0 into pa/pb
    auto load_chunk = [&](int c0) {
#pragma unroll
        for (int p = 0; p < 5; ++p) {
            const int m = am + 32 * p;
            const int c = c0 + akk;
            float4 v = make_float4(0.f, 0.f, 0.f, 0.f);
            if (c < CC) v = *(const float4*)(Wb + (size_t)m * CC + c);
            pa[p] = v;
        }
#pragma unroll
        for (int p = 0; p < 2; ++p) {
            const int c = c0 + bcr + 16 * p;
            float4 v = make_float4(0.f, 0.f, 0.f, 0.f);
            if (c < CC) v = *(const float4*)(Xb + (size_t)c * TT + bt);
            pb[p] = v;
        }
    };

    // ---- cvt/store regs into LDS buffer `buf`
    auto store_chunk = [&](int buf) {
#pragma unroll
        for (int p = 0; p < 5; ++p) {
            const int m = am + 32 * p;
            bf16x4 h = {(__bf16)pa[p].x, (__bf16)pa[p].y,
                        (__bf16)pa[p].z, (__bf16)pa[p].w};
            *(bf16x4*)&As[buf][m * LDA + akk] = h;       // b64, ~2-way banks
        }
#pragma unroll
        for (int p = 0; p < 2; ++p) {
            const int cr = bcr + 16 * p;
            float* row = &Bs[buf][cr * LDB2 + bt];       // natural layout, b64 x2
            *(float2*)(row + 0) = make_float2(pb[p].x, pb[p].y);
            *(float2*)(row + 2) = make_float2(pb[p].z, pb[p].w);
        }
    };

    // ---- pipeline fill
    load_chunk(0);
    store_chunk(0);          // vmcnt wait here (fill cost, once)
    load_chunk(KC);          // chunk 1 in flight across barrier
    BAR();

    for (int kc = 0; kc < NCHUNK; ++kc) {
        const int cur = kc & 1;

        // B-frags: gather 8 f32 per frag from natural [c][t] (2-way banks, free)
        bf16x8 bfr[2];
#pragma unroll
        for (int nt = 0; nt < 2; ++nt) {
            const int tcol = wn * 32 + nt * 16 + l16;
            bf16x8 h;
#pragma unroll
            for (int j = 0; j < 8; ++j)
                h[j] = (__bf16)Bs[cur][(quad * 8 + j) * LDB2 + tcol];
            bfr[nt] = h;
        }

#pragma unroll
        for (int mt = 0; mt < 5; ++mt) {
            bf16x8 af = *(const bf16x8*)&As[cur][(wm * 80 + mt * 16 + l16) * LDA + quad * 8];
#pragma unroll
            for (int nt = 0; nt < 2; ++nt)
                acc[mt][nt] = __builtin_amdgcn_mfma_f32_16x16x32_bf16(
                    af, bfr[nt], acc[mt][nt], 0, 0, 0);
        }

        if (kc + 1 < NCHUNK) {
            store_chunk(1 - cur);                 // chunk kc+1 (vmcnt hidden: issued 1 iter ago)
            if (kc + 2 < NCHUNK) load_chunk((kc + 2) * KC);
            BAR();
        }
    }

    // ---- epilogue: D[m = quad*4 + r][n = l16]
#pragma unroll
    for (int mt = 0; mt < 5; ++mt) {
        const int d = d0 + wm * 80 + mt * 16 + quad * 4;
#pragma unroll
        for (int nt = 0; nt < 2; ++nt) {
            float* ob = out + ((size_t)b * DD1 + d) * TT + T0 + wn * 32 + nt * 16 + l16;
#pragma unroll
            for (int r = 0; r < 4; ++r)
                ob[(size_t)r * TT] = acc[mt][nt][r];
        }
    }
}

extern "C" void kernel_launch(void* const* d_in, const int* in_sizes, int n_in,
                              void* d_out, int out_size, void* d_ws, size_t ws_size,
                              hipStream_t stream) {
    const float* X    = (const float*)d_in[0];   // [B, C, T]
    const int*   sidx = (const int*)  d_in[1];   // [B]
    const float* W    = (const float*)d_in[2];   // [S, D1, C]
    float*       out  = (float*)d_out;           // [B, D1, T]

    dim3 grid(BB, TT / NT, 2);   // 128 x 8 x 2 = 2048 blocks
    dim3 block(256);
    subj_conv_mfma<<<grid, block, 0, stream>>>(X, sidx, W, out);
}